// Round 6
// baseline (188.015 us; speedup 1.0000x reference)
//
#include <hip/hip_runtime.h>

typedef unsigned short u16;
typedef unsigned int   u32;

#define B_ 2
#define C_ 128
#define T_ 512
#define F_ 64
#define H_ 32
#define D_ 32

// ---- d_out scratch (float offsets): xm1/xf1 fp32 intermediates live in d_out ----
#define XM1_OUT 0u
#define XF1_OUT 2097152u

// ---- d_ws layout (float offsets) ----
#define CORR_OFF 0u          // padded corr: [b][h][518][34]; halo handled in k3 stager
#define WQ_OFF   1127168u    // softmax weights [b][512][32]

// ---------------- K1: projections xm1 = W^T@X + b, LDS-staged for MLP ----------------
// 512 blocks: [b(2) x sel(2) x 128 m-blocks of 256]. Thread = 1 m-column, 32 h-accs.
__global__ __launch_bounds__(256) void k1_proj(const float* __restrict__ xm, const float* __restrict__ xf,
                                               const float* __restrict__ w1, const float* __restrict__ b1,
                                               const float* __restrict__ w2, const float* __restrict__ b2,
                                               float* __restrict__ xm1, float* __restrict__ xf1){
  int blk  = blockIdx.x;
  int mblk = blk & 127;
  int bt   = blk >> 7;           // 0..3
  int b    = bt >> 1, sel = bt & 1;
  int tid  = threadIdx.x;
  int m0   = mblk * 256;

  const float* X    = (sel ? xf : xm) + (size_t)b * (C_*T_*F_);
  const float* W    = sel ? w2 : w1;
  const float* bias = sel ? b2 : b1;

  __shared__ float ls[32*256];   // 32 c-rows x 256 m

  float acc[H_];
#pragma unroll
  for (int h = 0; h < H_; h++) acc[h] = 0.f;

  for (int cc = 0; cc < C_; cc += 32){
    // stage 32x256 tile: 2048 float4, 8 per thread, all independent (8-deep MLP)
    for (int idx = tid; idx < 32*64; idx += 256){
      int r = idx >> 6, q = idx & 63;
      *(float4*)(ls + r*256 + q*4) =
        *(const float4*)(X + (size_t)(cc + r) * (T_*F_) + m0 + q*4);
    }
    __syncthreads();
#pragma unroll
    for (int r = 0; r < 32; r++){
      float x = ls[r*256 + tid];
      const float* Wr = W + (cc + r) * H_;
#pragma unroll
      for (int h = 0; h < H_; h++) acc[h] += x * Wr[h];
    }
    __syncthreads();
  }

  float* O = (sel ? xf1 : xm1) + (size_t)b * (H_*T_*F_) + m0 + tid;
#pragma unroll
  for (int h = 0; h < H_; h++) O[(size_t)h * (T_*F_)] = acc[h] + bias[h];
}

// ---------------- K2: corr[b,h,t,d] = sum_f xm1[b,h,t,f] * xf1[b,h,t+d-31,f] ----------------
__global__ __launch_bounds__(256) void k2_corr(const float* __restrict__ xm1, const float* __restrict__ xf1,
                                               float* __restrict__ corr_pad){
  int blk = blockIdx.x;
  int tt = blk & 7, h = (blk >> 3) & 31, b = blk >> 8;
  int t0 = tt * 64;
  const float* A  = xm1 + ((size_t)(b*H_ + h)) * (T_*F_);
  const float* Bm = xf1 + ((size_t)(b*H_ + h)) * (T_*F_);

  __shared__ float Al[64*68];
  __shared__ float Bl[95*68];
  int tid = threadIdx.x;

  for (int idx = tid; idx < 64*16; idx += 256){
    int r = idx >> 4, q = idx & 15;
    *(float4*)(Al + r*68 + q*4) = *(const float4*)(A + (size_t)(t0 + r)*F_ + q*4);
  }
  for (int idx = tid; idx < 95*16; idx += 256){
    int r = idx >> 4, q = idx & 15;
    int gr = t0 - 31 + r;
    float4 v = make_float4(0.f,0.f,0.f,0.f);
    if (gr >= 0) v = *(const float4*)(Bm + (size_t)gr*F_ + q*4);
    *(float4*)(Bl + r*68 + q*4) = v;
  }
  __syncthreads();

  int tl = tid >> 2, dg = tid & 3;
  float acc[8];
#pragma unroll
  for (int j = 0; j < 8; j++) acc[j] = 0.f;

  for (int fq = 0; fq < 16; fq++){
    float4 a = *(const float4*)(Al + tl*68 + fq*4);
#pragma unroll
    for (int j = 0; j < 8; j++){
      float4 bv = *(const float4*)(Bl + (tl + dg*8 + j)*68 + fq*4);
      acc[j] += a.x*bv.x + a.y*bv.y + a.z*bv.z + a.w*bv.w;
    }
  }
  float* o = corr_pad + ((size_t)(b*H_ + h))*(518*34) + (size_t)(t0 + tl + 3)*34 + (dg*8 + 1);
#pragma unroll
  for (int j = 0; j < 8; j++) o[j] = acc[j];
}

// ---------------- K3: 5x3 conv over (t,d) summing h + bc, causal mask, softmax over d ----------------
// Halo (rows <3, >514; cols 0,33) zeroed in the stager predicate — no pre-init of corr_pad needed.
__global__ __launch_bounds__(256) void k3_conv_softmax(const float* __restrict__ corr_pad,
                                                       const float* __restrict__ wc, const float* __restrict__ bc,
                                                       float* __restrict__ wq){
  int b  = blockIdx.x >> 6;
  int t0 = (blockIdx.x & 63) * 8;
  int tid = threadIdx.x;

  __shared__ float ls[32*12*34];   // [h][12 rows t0..t0+11][34 d]
  const float* cp = corr_pad + (size_t)b * (H_*518*34);
  for (int idx = tid; idx < 32*12*34; idx += 256){
    int h = idx / 408, rem = idx - h*408;
    int r = rem / 34, dd = rem - r*34;
    int gr = t0 + r;
    bool halo = (gr < 3) | (gr > 514) | (dd == 0) | (dd == 33);
    ls[idx] = halo ? 0.f : cp[(size_t)h*(518*34) + (size_t)gr*34 + dd];
  }
  __syncthreads();

  int tl = tid >> 5, d = tid & 31;
  int t = t0 + tl;

  float val = bc[0];
  for (int h = 0; h < H_; h++){
    const float* base = ls + h*408 + tl*34 + d;
    const float* wch = wc + h*15;
#pragma unroll
    for (int kh = 0; kh < 5; kh++){
#pragma unroll
      for (int kw = 0; kw < 3; kw++){
        val += base[kh*34 + kw] * wch[kh*3 + kw];
      }
    }
  }
  if (t + d < D_ - 1) val = -1e13f;

  float m = val;
#pragma unroll
  for (int off = 16; off > 0; off >>= 1) m = fmaxf(m, __shfl_xor(m, off));
  float e = __expf(val - m);
  float s = e;
#pragma unroll
  for (int off = 16; off > 0; off >>= 1) s += __shfl_xor(s, off);

  wq[((size_t)b*T_ + t)*D_ + d] = e / s;
}

// ---------------- K4: out[b,c,t,f] = sum_d w[b,t,d] * xf[b,c,t+d-31,f] ----------------
__global__ __launch_bounds__(256) void k4_out(const float* __restrict__ xf, const float* __restrict__ wq,
                                              float* __restrict__ out){
  int blk = blockIdx.x;
  int tt = blk & 7, c = (blk >> 3) & 127, b = blk >> 10;
  int t0 = tt * 64;
  const float* Xf = xf + ((size_t)(b*C_ + c)) * (T_*F_);

  __shared__ float xfl[95*68];
  __shared__ float wl[64*33];
  int tid = threadIdx.x;

  for (int idx = tid; idx < 95*16; idx += 256){
    int r = idx >> 4, q = idx & 15;
    int gr = t0 - 31 + r;
    float4 v = make_float4(0.f,0.f,0.f,0.f);
    if (gr >= 0) v = *(const float4*)(Xf + (size_t)gr*F_ + q*4);
    *(float4*)(xfl + r*68 + q*4) = v;
  }
  for (int idx = tid; idx < 64*8; idx += 256){
    int r = idx >> 3, q = idx & 7;
    float4 v = *(const float4*)(wq + ((size_t)b*T_ + t0 + r)*D_ + q*4);
    wl[r*33 + q*4 + 0] = v.x; wl[r*33 + q*4 + 1] = v.y;
    wl[r*33 + q*4 + 2] = v.z; wl[r*33 + q*4 + 3] = v.w;
  }
  __syncthreads();

  int tg = tid >> 4, q = tid & 15;
  float4 acc[4];
#pragma unroll
  for (int j = 0; j < 4; j++) acc[j] = make_float4(0.f,0.f,0.f,0.f);

#pragma unroll
  for (int rr = 0; rr < 35; rr++){
    float4 xv = *(const float4*)(xfl + (tg*4 + rr)*68 + q*4);
#pragma unroll
    for (int j = 0; j < 4; j++){
      int d = rr - j;
      if (d >= 0 && d < D_){
        float wv = wl[(tg*4 + j)*33 + d];
        acc[j].x += wv * xv.x; acc[j].y += wv * xv.y;
        acc[j].z += wv * xv.z; acc[j].w += wv * xv.w;
      }
    }
  }
#pragma unroll
  for (int j = 0; j < 4; j++){
    int t = t0 + tg*4 + j;
    float* O = out + (((size_t)(b*C_ + c))*T_ + t)*F_ + q*4;
    *(float4*)O = acc[j];
  }
}

extern "C" void kernel_launch(void* const* d_in, const int* in_sizes, int n_in,
                              void* d_out, int out_size, void* d_ws, size_t ws_size,
                              hipStream_t stream) {
  const float* xm = (const float*)d_in[0];
  const float* xf = (const float*)d_in[1];
  const float* w1 = (const float*)d_in[2];
  const float* b1 = (const float*)d_in[3];
  const float* w2 = (const float*)d_in[4];
  const float* b2 = (const float*)d_in[5];
  const float* wc = (const float*)d_in[6];
  const float* bc = (const float*)d_in[7];
  float* ws = (float*)d_ws;

  // fp32 intermediates xm1/xf1 live in d_out; k4 reads only xf/wq then overwrites it.
  float* xm1 = (float*)d_out + XM1_OUT;
  float* xf1 = (float*)d_out + XF1_OUT;

  hipLaunchKernelGGL(k1_proj, dim3(512), dim3(256), 0, stream, xm, xf, w1, b1, w2, b2, xm1, xf1);
  hipLaunchKernelGGL(k2_corr, dim3(512), dim3(256), 0, stream, xm1, xf1, ws + CORR_OFF);
  hipLaunchKernelGGL(k3_conv_softmax, dim3(128), dim3(256), 0, stream, ws + CORR_OFF, wc, bc, ws + WQ_OFF);
  hipLaunchKernelGGL(k4_out, dim3(2048), dim3(256), 0, stream, xf, ws + WQ_OFF, (float*)d_out);
}

// Round 7
// 184.880 us; speedup vs baseline: 1.0170x; 1.0170x over previous
//
#include <hip/hip_runtime.h>

typedef unsigned short u16;
typedef unsigned int   u32;

#define B_ 2
#define C_ 128
#define T_ 512
#define F_ 64
#define H_ 32
#define D_ 32

// ---- d_out scratch (float offsets): xm1/xf1 fp32 intermediates live in d_out ----
#define XM1_OUT 0u
#define XF1_OUT 2097152u

// ---- d_ws layout (float offsets) ----
#define CORR_OFF 0u          // padded corr: [b][h][518][34]; halo handled in k3 stager
#define WQ_OFF   1127168u    // softmax weights [b][512][32]

// ---------------- K1: projections xm1 = W^T@X + b ----------------
// Barrier-free: 1 m-column/thread, acc[32], 16-deep independent load batches.
// acc32+xv16+addr ~= 55 VGPR -> no pressure, loads stay hoisted (R4 failed at acc64).
__global__ __launch_bounds__(256) void k1_proj(const float* __restrict__ xm, const float* __restrict__ xf,
                                               const float* __restrict__ w1, const float* __restrict__ b1,
                                               const float* __restrict__ w2, const float* __restrict__ b2,
                                               float* __restrict__ xm1, float* __restrict__ xf1){
  int blk  = blockIdx.x;
  int mblk = blk & 127;
  int bt   = blk >> 7;           // 0..3
  int b    = bt >> 1, sel = bt & 1;
  int m    = mblk * 256 + threadIdx.x;

  const float* X    = (sel ? xf : xm) + (size_t)b * (C_*T_*F_) + m;
  const float* W    = sel ? w2 : w1;
  const float* bias = sel ? b2 : b1;

  float acc[H_];
#pragma unroll
  for (int h = 0; h < H_; h++) acc[h] = 0.f;

  for (int c0 = 0; c0 < C_; c0 += 16){
    float xv[16];
#pragma unroll
    for (int u = 0; u < 16; u++)
      xv[u] = X[(size_t)(c0 + u) * (T_*F_)];
#pragma unroll
    for (int u = 0; u < 16; u++){
      const float* Wr = W + (c0 + u) * H_;   // wave-uniform -> s_load, hits K$
#pragma unroll
      for (int h = 0; h < H_; h++) acc[h] = fmaf(xv[u], Wr[h], acc[h]);
    }
  }

  float* O = (sel ? xf1 : xm1) + (size_t)b * (H_*T_*F_) + m;
#pragma unroll
  for (int h = 0; h < H_; h++) O[(size_t)h * (T_*F_)] = acc[h] + bias[h];
}

// ---------------- K2: corr[b,h,t,d] = sum_f xm1[b,h,t,f] * xf1[b,h,t+d-31,f] ----------------
__global__ __launch_bounds__(256) void k2_corr(const float* __restrict__ xm1, const float* __restrict__ xf1,
                                               float* __restrict__ corr_pad){
  int blk = blockIdx.x;
  int tt = blk & 7, h = (blk >> 3) & 31, b = blk >> 8;
  int t0 = tt * 64;
  const float* A  = xm1 + ((size_t)(b*H_ + h)) * (T_*F_);
  const float* Bm = xf1 + ((size_t)(b*H_ + h)) * (T_*F_);

  __shared__ float Al[64*68];
  __shared__ float Bl[95*68];
  int tid = threadIdx.x;

  for (int idx = tid; idx < 64*16; idx += 256){
    int r = idx >> 4, q = idx & 15;
    *(float4*)(Al + r*68 + q*4) = *(const float4*)(A + (size_t)(t0 + r)*F_ + q*4);
  }
  for (int idx = tid; idx < 95*16; idx += 256){
    int r = idx >> 4, q = idx & 15;
    int gr = t0 - 31 + r;
    float4 v = make_float4(0.f,0.f,0.f,0.f);
    if (gr >= 0) v = *(const float4*)(Bm + (size_t)gr*F_ + q*4);
    *(float4*)(Bl + r*68 + q*4) = v;
  }
  __syncthreads();

  int tl = tid >> 2, dg = tid & 3;
  float acc[8];
#pragma unroll
  for (int j = 0; j < 8; j++) acc[j] = 0.f;

  for (int fq = 0; fq < 16; fq++){
    float4 a = *(const float4*)(Al + tl*68 + fq*4);
#pragma unroll
    for (int j = 0; j < 8; j++){
      float4 bv = *(const float4*)(Bl + (tl + dg*8 + j)*68 + fq*4);
      acc[j] += a.x*bv.x + a.y*bv.y + a.z*bv.z + a.w*bv.w;
    }
  }
  float* o = corr_pad + ((size_t)(b*H_ + h))*(518*34) + (size_t)(t0 + tl + 3)*34 + (dg*8 + 1);
#pragma unroll
  for (int j = 0; j < 8; j++) o[j] = acc[j];
}

// ---------------- K3: 5x3 conv over (t,d) summing h + bc, causal mask, softmax over d ----------------
__global__ __launch_bounds__(256) void k3_conv_softmax(const float* __restrict__ corr_pad,
                                                       const float* __restrict__ wc, const float* __restrict__ bc,
                                                       float* __restrict__ wq){
  int b  = blockIdx.x >> 6;
  int t0 = (blockIdx.x & 63) * 8;
  int tid = threadIdx.x;

  __shared__ float ls[32*12*34];   // [h][12 rows t0..t0+11][34 d]
  const float* cp = corr_pad + (size_t)b * (H_*518*34);
  for (int idx = tid; idx < 32*12*34; idx += 256){
    int h = idx / 408, rem = idx - h*408;
    int r = rem / 34, dd = rem - r*34;
    int gr = t0 + r;
    bool halo = (gr < 3) | (gr > 514) | (dd == 0) | (dd == 33);
    ls[idx] = halo ? 0.f : cp[(size_t)h*(518*34) + (size_t)gr*34 + dd];
  }
  __syncthreads();

  int tl = tid >> 5, d = tid & 31;
  int t = t0 + tl;

  float val = bc[0];
  for (int h = 0; h < H_; h++){
    const float* base = ls + h*408 + tl*34 + d;
    const float* wch = wc + h*15;
#pragma unroll
    for (int kh = 0; kh < 5; kh++){
#pragma unroll
      for (int kw = 0; kw < 3; kw++){
        val += base[kh*34 + kw] * wch[kh*3 + kw];
      }
    }
  }
  if (t + d < D_ - 1) val = -1e13f;

  float m = val;
#pragma unroll
  for (int off = 16; off > 0; off >>= 1) m = fmaxf(m, __shfl_xor(m, off));
  float e = __expf(val - m);
  float s = e;
#pragma unroll
  for (int off = 16; off > 0; off >>= 1) s += __shfl_xor(s, off);

  wq[((size_t)b*T_ + t)*D_ + d] = e / s;
}

// ---------------- K4: out[b,c,t,f] = sum_d w[b,t,d] * xf[b,c,t+d-31,f] ----------------
__global__ __launch_bounds__(256) void k4_out(const float* __restrict__ xf, const float* __restrict__ wq,
                                              float* __restrict__ out){
  int blk = blockIdx.x;
  int tt = blk & 7, c = (blk >> 3) & 127, b = blk >> 10;
  int t0 = tt * 64;
  const float* Xf = xf + ((size_t)(b*C_ + c)) * (T_*F_);

  __shared__ float xfl[95*68];
  __shared__ float wl[64*33];
  int tid = threadIdx.x;

  for (int idx = tid; idx < 95*16; idx += 256){
    int r = idx >> 4, q = idx & 15;
    int gr = t0 - 31 + r;
    float4 v = make_float4(0.f,0.f,0.f,0.f);
    if (gr >= 0) v = *(const float4*)(Xf + (size_t)gr*F_ + q*4);
    *(float4*)(xfl + r*68 + q*4) = v;
  }
  for (int idx = tid; idx < 64*8; idx += 256){
    int r = idx >> 3, q = idx & 7;
    float4 v = *(const float4*)(wq + ((size_t)b*T_ + t0 + r)*D_ + q*4);
    wl[r*33 + q*4 + 0] = v.x; wl[r*33 + q*4 + 1] = v.y;
    wl[r*33 + q*4 + 2] = v.z; wl[r*33 + q*4 + 3] = v.w;
  }
  __syncthreads();

  int tg = tid >> 4, q = tid & 15;
  float4 acc[4];
#pragma unroll
  for (int j = 0; j < 4; j++) acc[j] = make_float4(0.f,0.f,0.f,0.f);

#pragma unroll
  for (int rr = 0; rr < 35; rr++){
    float4 xv = *(const float4*)(xfl + (tg*4 + rr)*68 + q*4);
#pragma unroll
    for (int j = 0; j < 4; j++){
      int d = rr - j;
      if (d >= 0 && d < D_){
        float wv = wl[(tg*4 + j)*33 + d];
        acc[j].x += wv * xv.x; acc[j].y += wv * xv.y;
        acc[j].z += wv * xv.z; acc[j].w += wv * xv.w;
      }
    }
  }
#pragma unroll
  for (int j = 0; j < 4; j++){
    int t = t0 + tg*4 + j;
    float* O = out + (((size_t)(b*C_ + c))*T_ + t)*F_ + q*4;
    *(float4*)O = acc[j];
  }
}

extern "C" void kernel_launch(void* const* d_in, const int* in_sizes, int n_in,
                              void* d_out, int out_size, void* d_ws, size_t ws_size,
                              hipStream_t stream) {
  const float* xm = (const float*)d_in[0];
  const float* xf = (const float*)d_in[1];
  const float* w1 = (const float*)d_in[2];
  const float* b1 = (const float*)d_in[3];
  const float* w2 = (const float*)d_in[4];
  const float* b2 = (const float*)d_in[5];
  const float* wc = (const float*)d_in[6];
  const float* bc = (const float*)d_in[7];
  float* ws = (float*)d_ws;

  float* xm1 = (float*)d_out + XM1_OUT;
  float* xf1 = (float*)d_out + XF1_OUT;

  hipLaunchKernelGGL(k1_proj, dim3(512), dim3(256), 0, stream, xm, xf, w1, b1, w2, b2, xm1, xf1);
  hipLaunchKernelGGL(k2_corr, dim3(512), dim3(256), 0, stream, xm1, xf1, ws + CORR_OFF);
  hipLaunchKernelGGL(k3_conv_softmax, dim3(128), dim3(256), 0, stream, ws + CORR_OFF, wc, bc, ws + WQ_OFF);
  hipLaunchKernelGGL(k4_out, dim3(2048), dim3(256), 0, stream, xf, ws + WQ_OFF, (float*)d_out);
}